// Round 7
// baseline (550.990 us; speedup 1.0000x reference)
//
#include <hip/hip_runtime.h>
#include <cstddef>

typedef _Float16 h2    __attribute__((ext_vector_type(2)));
typedef _Float16 half8 __attribute__((ext_vector_type(8)));
typedef float    f32x4 __attribute__((ext_vector_type(4)));

#define CH    192
#define CWID  640
#define IMG_H 384
#define IMG_W 1280
#define TW    128
#define GR    224      // g rows staged
#define RAWC  179      // 66 fl cols + 113 g cols (+pad to 192)
#define RAWP  192

__device__ __forceinline__ float fastrcp(float x) {
#if __has_builtin(__builtin_amdgcn_rcpf)
  return __builtin_amdgcn_rcpf(x);
#else
  return 1.0f / x;
#endif
}
__device__ __forceinline__ float fastexp2(float x) {
#if __has_builtin(__builtin_amdgcn_exp2f)
  return __builtin_amdgcn_exp2f(x);
#else
  return exp2f(x);
#endif
}
// xor-16 within 32-lane halves: BitMode offset = (16<<10)|0x1F
__device__ __forceinline__ float swz16(float x) {
  return __uint_as_float((unsigned)__builtin_amdgcn_ds_swizzle((int)__float_as_uint(x), 0x401F));
}
__device__ __forceinline__ float bperm(int addr, float x) {
  return __uint_as_float((unsigned)__builtin_amdgcn_ds_bpermute(addr, (int)__float_as_uint(x)));
}

// ---------------- Kernel 1: 3x3 stride-2 SAME conv + bias + ReLU -> f16 ----------------
// Named-scalar operands only (no aggregate allocas -> no scratch). Per input row:
// f01,f23,f45 always in-row; f67,f8 guarded (ow==639 would read 1 past the image and
// must be zero per SAME padding anyway). Row guard ir<IMG_H zero-fills (fma(0,..) exact).
__global__ __launch_bounds__(256, 6)
void conv_relu_kernel(const float* __restrict__ xl, const float* __restrict__ xr,
                      const float* __restrict__ Wt, const float* __restrict__ bias,
                      _Float16* __restrict__ Fc) {
  __shared__ float wl[864];
  __shared__ float bl[32];
  const int tid = threadIdx.x;
  for (int t = tid; t < 864; t += 256) wl[t] = Wt[t];
  if (tid < 32) bl[tid] = bias[tid];
  __syncthreads();

  const int dow = tid & 127;
  const int doh = tid >> 7;
  const int ow = blockIdx.x * 128 + dow;
  const int oh = blockIdx.y * 2 + doh;
  const int bb = blockIdx.z;
  const float* src = (bb < 2) ? (xl + (size_t)bb * IMG_H * IMG_W * 3)
                              : (xr + (size_t)(bb - 2) * IMG_H * IMG_W * 3);
  const float* base = src + ((size_t)(oh * 2) * IMG_W + ow * 2) * 3;
  const bool colok = (ow < CWID - 1);

  float acc[32];
  #pragma unroll
  for (int c = 0; c < 32; ++c) acc[c] = bl[c];

  #pragma unroll
  for (int kh = 0; kh < 3; ++kh) {
    const int ir = oh * 2 + kh;
    float2 f01 = {0.f, 0.f}, f23 = {0.f, 0.f}, f45 = {0.f, 0.f}, f67 = {0.f, 0.f};
    float f8 = 0.f;
    if (ir < IMG_H) {
      const float* rp = base + (size_t)kh * IMG_W * 3;
      f01 = *(const float2*)(rp + 0);
      f23 = *(const float2*)(rp + 2);
      f45 = *(const float2*)(rp + 4);
      if (colok) {
        f67 = *(const float2*)(rp + 6);
        f8  = rp[8];
      }
    }
    const float v0 = f01.x, v1 = f01.y, v2 = f23.x;
    const float v3 = f23.y, v4 = f45.x, v5 = f45.y;
    const float v6 = f67.x, v7 = f67.y, v8 = f8;
    #pragma unroll
    for (int e = 0; e < 9; ++e) {
      const float v = (e == 0) ? v0 : (e == 1) ? v1 : (e == 2) ? v2 :
                      (e == 3) ? v3 : (e == 4) ? v4 : (e == 5) ? v5 :
                      (e == 6) ? v6 : (e == 7) ? v7 : v8;
      const float* wp = &wl[(kh * 9 + e) * 32];   // ((kh*3+kw)*3+ci)*32, e = kw*3+ci
      #pragma unroll
      for (int c8 = 0; c8 < 8; ++c8) {
        const float4 w4 = *(const float4*)(wp + c8 * 4);
        acc[c8 * 4 + 0] = fmaf(v, w4.x, acc[c8 * 4 + 0]);
        acc[c8 * 4 + 1] = fmaf(v, w4.y, acc[c8 * 4 + 1]);
        acc[c8 * 4 + 2] = fmaf(v, w4.z, acc[c8 * 4 + 2]);
        acc[c8 * 4 + 3] = fmaf(v, w4.w, acc[c8 * 4 + 3]);
      }
    }
  }

  const size_t g = ((size_t)bb * CH + oh) * CWID + ow;
  half8* dst = (half8*)(Fc + g * 32);
  #pragma unroll
  for (int q = 0; q < 4; ++q) {
    half8 o;
    #pragma unroll
    for (int e = 0; e < 8; ++e) o[e] = (_Float16)fmaxf(acc[q * 8 + e], 0.f);
    dst[q] = o;
  }
}

// ------- Kernel 2: f16 MFMA cost volume + soft-argmin (unchanged from R6) -------
__global__ __launch_bounds__(256, 4)
void disparity_mfma_kernel(const _Float16* __restrict__ Fc, float* __restrict__ out) {
  __shared__ alignas(16) _Float16 raw[RAWP * 32];   // 12.3 KB (rows 179..191 = pad)
  __shared__ alignas(16) _Float16 flH[8 * 512];     // 8 tiles [16][32] f16
  __shared__ alignas(16) _Float16 gH[14 * 512];     // 14 tiles
  __shared__ alignas(16) float As[TW];
  __shared__ alignas(16) float Bs[GR];

  const int tid = threadIdx.x;
  const int w0  = blockIdx.x * TW;
  const int h   = blockIdx.y;
  const int bz  = blockIdx.z;

  // vertical bilinear params (half-pixel, clamped)
  const int hk = h >> 1;
  int r0, r1; float wv0;
  if (h & 1) { r0 = hk; r1 = (hk + 1 > CH - 1) ? CH - 1 : hk + 1; wv0 = 0.75f; }
  else       { r0 = (hk - 1 < 0) ? 0 : hk - 1; r1 = hk;           wv0 = 0.25f; }
  const half8 w0v = (half8)(_Float16)wv0;
  const half8 w1v = (half8)(_Float16)(1.0f - wv0);

  const int vbaseL = (w0 >> 1) + 639;  // fl raw region (t 0..65)
  const int vbaseR = (w0 >> 1) + 592;  // g raw region (t 66..178)

  char* const rawB = (char*)raw;

  // scalar row bases (hoisted 64-bit math)
  const char* const bL0 = (const char*)(Fc + ((size_t)bz * CH + r0) * CWID * 32);
  const char* const bL1 = (const char*)(Fc + ((size_t)bz * CH + r1) * CWID * 32);
  const char* const bR0 = (const char*)(Fc + ((size_t)(bz + 2) * CH + r0) * CWID * 32);
  const char* const bR1 = (const char*)(Fc + ((size_t)(bz + 2) * CH + r1) * CWID * 32);

  // ---- Phase 0: stage + vertical blend; 3 uniform tasks/thread (768 = 192*4) ----
  #pragma unroll
  for (int it = 0; it < 3; ++it) {
    const int task = tid + it * 256;
    const int t    = task >> 2;                     // 0..191 (179+ = pad)
    const int tc   = (t > RAWC - 1) ? RAWC - 1 : t; // clamp for address only
    const int c16  = task & 3;
    const bool isfl = tc < 66;
    int v = isfl ? (vbaseL + tc) : (vbaseR + tc - 66);  // in [592, 1280]
    v -= (v >= 640) ? 640 : 0;
    v -= (v >= 640) ? 640 : 0;                          // 1280 -> 0 (roll wrap)
    const char* p0 = isfl ? bL0 : bR0;
    const char* p1 = isfl ? bL1 : bR1;
    const int off = (v << 6) + (c16 << 4);
    const half8 a0 = *(const half8*)(p0 + off);
    const half8 a1 = *(const half8*)(p1 + off);
    const half8 vv = a0 * w0v + a1 * w1v;
    *(half8*)(rawB + t * 64 + ((c16 ^ (t & 3)) << 4)) = vv;
  }
  __syncthreads();

  // ---- Phase 1: horizontal blend + MFMA tiles + norms (same f16 values) ----
  const _Float16 h75 = (_Float16)0.75f, h25 = (_Float16)0.25f;
  auto row_body = [&](int row) {
    const bool isfl = row < TW;
    const int r  = isfl ? row : row - TW;
    const int uv = isfl ? (w0 + r) : (w0 - 95 + r);
    const int uact = uv < 0 ? uv + IMG_W : (uv >= IMG_W ? uv - IMG_W : uv);
    const int up = uv + IMG_W;                       // positive, same parity
    const int vm0 = (up - 1) >> 1;                   // branch-free taps
    int t0 = vm0 - (isfl ? vbaseL : (vbaseR - 66));
    int t1 = t0 + 1;
    if (uact == 0)         t0 = t1;   // left-edge clamp
    if (uact == IMG_W - 1) t1 = t0;   // right-edge clamp
    const _Float16 hw0 = (up & 1) ? h75 : h25;
    const _Float16 hw1 = (up & 1) ? h25 : h75;
    const half8 h0v = (half8)hw0;
    const half8 h1v = (half8)hw1;
    const char* r0p = rawB + t0 * 64;
    const char* r1p = rawB + t1 * 64;
    const int k0s = t0 & 3, k1s = t1 & 3;
    const int rr  = r & 15;
    char* dstB = (char*)(isfl ? flH : gH) + (r >> 4) * 1024 + rr * 64;
    float s = 0.f;
    #pragma unroll
    for (int c16 = 0; c16 < 4; ++c16) {
      const half8 a = *(const half8*)(r0p + ((c16 ^ k0s) << 4));
      const half8 b = *(const half8*)(r1p + ((c16 ^ k1s) << 4));
      const half8 v = a * h0v + b * h1v;
      #pragma unroll
      for (int e = 0; e < 4; ++e) {
        h2 pe = {v[2 * e], v[2 * e + 1]};
#if __has_builtin(__builtin_amdgcn_fdot2)
        s = __builtin_amdgcn_fdot2(pe, pe, s, false);
#else
        s += (float)pe[0] * (float)pe[0] + (float)pe[1] * (float)pe[1];
#endif
      }
      *(half8*)(dstB + ((c16 ^ (rr & 3)) << 4)) = v;
    }
    if (isfl) As[r] = s; else Bs[r] = s;
  };
  row_body(tid);
  if (tid < TW + GR - 256) row_body(tid + 256);
  __syncthreads();

  // ---- Phase 2: MFMA band + per-pixel soft-argmin ----
  const int lane = tid & 63;
  const int wid  = tid >> 6;
  const int n  = lane & 15;   // fl row within tile (C col)
  const int gq = lane >> 4;   // k-slice / C row group
  const int foffB = n * 64 + ((gq ^ (n & 3)) << 4);
  const int bpaddr = (lane ^ 32) << 2;   // shared xor-32 bpermute address

  #pragma unroll
  for (int pp = 0; pp < 2; ++pp) {
    const int p = wid * 2 + pp;          // i-tile 0..7
    const half8 bfrag = *(const half8*)((const char*)flH + p * 1024 + foffB);
    f32x4 acc[7];
    #pragma unroll
    for (int dq = 0; dq < 7; ++dq) {
      const half8 afrag = *(const half8*)((const char*)gH + (p + dq) * 1024 + foffB);
      f32x4 z = {0.f, 0.f, 0.f, 0.f};
      acc[dq] = __builtin_amdgcn_mfma_f32_16x16x32_f16(afrag, bfrag, z, 0, 0, 0);
    }

    // pass 1: cost + min/max (invalid cells -> +3e38 so pass 2 is mask-free;
    // min/max paired for v_min3/v_max3 fusion — exact, min/max associative)
    const float Ai = As[p * 16 + n];
    float cv[7][4];
    float mn = 3.0e38f, mx = -3.0e38f;
    #pragma unroll
    for (int dq = 0; dq < 7; ++dq) {
      const f32x4 b4 = *(const f32x4*)(&Bs[(p + dq) * 16 + gq * 4]);
      float cm[4], cx[4];
      #pragma unroll
      for (int rg = 0; rg < 4; ++rg) {
        const int m = gq * 4 + rg;
        const float cc = fmaf(-2.f, acc[dq][rg], Ai + b4[rg]);
        const bool valid = (dq != 0 || m >= n) && (dq != 6 || m < n);
        cm[rg] = valid ? cc : 3.0e38f;
        cx[rg] = valid ? cc : -3.0e38f;
        cv[dq][rg] = cm[rg];
      }
      mn = fminf(mn, fminf(fminf(cm[0], cm[1]), fminf(cm[2], cm[3])));
      mx = fmaxf(mx, fmaxf(fmaxf(cx[0], cx[1]), fmaxf(cx[2], cx[3])));
    }
    mn = fminf(mn, swz16(mn));
    mx = fmaxf(mx, swz16(mx));
    mn = fminf(mn, bperm(bpaddr, mn));
    mx = fmaxf(mx, bperm(bpaddr, mx));

    // pass 2: mask-free softmax accumulation, 2 accumulator pairs for ILP
    const float ralpha = 177.0f * 1.4426950408889634f * fastrcp(mx);
    const float na   = -ralpha;
    const float base = ralpha * mn;
    float sw0 = 0.f, sdw0 = 0.f, sw1 = 0.f, sdw1 = 0.f;
    #pragma unroll
    for (int dq = 0; dq < 7; ++dq) {
      #pragma unroll
      for (int rg = 0; rg < 4; ++rg) {
        const int m = gq * 4 + rg;
        const float wgt = fastexp2(fmaf(na, cv[dq][rg], base));  // 0 for masked
        const float kf = (float)(95 - (dq * 16 + m - n));        // d = 95 - k
        if (rg & 2) { sw1 += wgt; sdw1 = fmaf(kf, wgt, sdw1); }
        else        { sw0 += wgt; sdw0 = fmaf(kf, wgt, sdw0); }
      }
    }
    float sw = sw0 + sw1, sdw = sdw0 + sdw1;
    sw  += swz16(sw);
    sdw += swz16(sdw);
    sw  += bperm(bpaddr, sw);
    sdw += bperm(bpaddr, sdw);
    if (gq == 0)
      out[((size_t)bz * IMG_H + h) * IMG_W + w0 + p * 16 + n] = sdw * fastrcp(sw);
  }
}

extern "C" void kernel_launch(void* const* d_in, const int* in_sizes, int n_in,
                              void* d_out, int out_size, void* d_ws, size_t ws_size,
                              hipStream_t stream) {
  (void)in_sizes; (void)n_in; (void)out_size; (void)ws_size;
  const float* xl   = (const float*)d_in[0];
  const float* xr   = (const float*)d_in[1];
  const float* Wt   = (const float*)d_in[2];
  const float* bias = (const float*)d_in[3];
  _Float16* Fc = (_Float16*)d_ws;   // conv features [4,192,640,32] f16 = 31.5 MB
  float* out = (float*)d_out;       // [2,384,1280] f32

  hipLaunchKernelGGL(conv_relu_kernel, dim3(5, 96, 4), dim3(256), 0, stream,
                     xl, xr, Wt, bias, Fc);
  hipLaunchKernelGGL(disparity_mfma_kernel, dim3(IMG_W / TW, IMG_H, 2), dim3(256), 0, stream,
                     Fc, out);
}

// Round 8
// 182.883 us; speedup vs baseline: 3.0128x; 3.0128x over previous
//
#include <hip/hip_runtime.h>
#include <cstddef>

typedef _Float16 h2    __attribute__((ext_vector_type(2)));
typedef _Float16 half8 __attribute__((ext_vector_type(8)));
typedef float    f32x4 __attribute__((ext_vector_type(4)));

#define CH    192
#define CWID  640
#define IMG_H 384
#define IMG_W 1280
#define TW    128
#define GR    224      // g rows staged
#define RAWC  179      // 66 fl cols + 113 g cols (+pad to 192)
#define RAWP  192

__device__ __forceinline__ float fastrcp(float x) {
#if __has_builtin(__builtin_amdgcn_rcpf)
  return __builtin_amdgcn_rcpf(x);
#else
  return 1.0f / x;
#endif
}
__device__ __forceinline__ float fastexp2(float x) {
#if __has_builtin(__builtin_amdgcn_exp2f)
  return __builtin_amdgcn_exp2f(x);
#else
  return exp2f(x);
#endif
}
// xor-16 within 32-lane halves: BitMode offset = (16<<10)|0x1F
__device__ __forceinline__ float swz16(float x) {
  return __uint_as_float((unsigned)__builtin_amdgcn_ds_swizzle((int)__float_as_uint(x), 0x401F));
}
__device__ __forceinline__ float bperm(int addr, float x) {
  return __uint_as_float((unsigned)__builtin_amdgcn_ds_bpermute(addr, (int)__float_as_uint(x)));
}

// ---------------- Kernel 1: 3x3 stride-2 SAME conv + bias + ReLU -> f16 ----------------
// Named-scalar operands only (no aggregate allocas -> no scratch). NO launch_bounds
// register cap: R7's (256,6) cap (~85 VGPR) made the allocator demote acc[32] to
// scratch (VGPR_Count=40, 1.1GB scratch writes, 507us). Default budget needs ~100.
__global__ __launch_bounds__(256)
void conv_relu_kernel(const float* __restrict__ xl, const float* __restrict__ xr,
                      const float* __restrict__ Wt, const float* __restrict__ bias,
                      _Float16* __restrict__ Fc) {
  __shared__ float wl[864];
  __shared__ float bl[32];
  const int tid = threadIdx.x;
  for (int t = tid; t < 864; t += 256) wl[t] = Wt[t];
  if (tid < 32) bl[tid] = bias[tid];
  __syncthreads();

  const int dow = tid & 127;
  const int doh = tid >> 7;
  const int ow = blockIdx.x * 128 + dow;
  const int oh = blockIdx.y * 2 + doh;
  const int bb = blockIdx.z;
  const float* src = (bb < 2) ? (xl + (size_t)bb * IMG_H * IMG_W * 3)
                              : (xr + (size_t)(bb - 2) * IMG_H * IMG_W * 3);
  const float* base = src + ((size_t)(oh * 2) * IMG_W + ow * 2) * 3;
  const bool colok = (ow < CWID - 1);

  float acc[32];
  #pragma unroll
  for (int c = 0; c < 32; ++c) acc[c] = bl[c];

  #pragma unroll
  for (int kh = 0; kh < 3; ++kh) {
    const int ir = oh * 2 + kh;
    float2 f01 = {0.f, 0.f}, f23 = {0.f, 0.f}, f45 = {0.f, 0.f}, f67 = {0.f, 0.f};
    float f8 = 0.f;
    if (ir < IMG_H) {
      const float* rp = base + (size_t)kh * IMG_W * 3;
      f01 = *(const float2*)(rp + 0);
      f23 = *(const float2*)(rp + 2);
      f45 = *(const float2*)(rp + 4);
      if (colok) {
        f67 = *(const float2*)(rp + 6);
        f8  = rp[8];
      }
    }
    const float v0 = f01.x, v1 = f01.y, v2 = f23.x;
    const float v3 = f23.y, v4 = f45.x, v5 = f45.y;
    const float v6 = f67.x, v7 = f67.y, v8 = f8;
    #pragma unroll
    for (int e = 0; e < 9; ++e) {
      const float v = (e == 0) ? v0 : (e == 1) ? v1 : (e == 2) ? v2 :
                      (e == 3) ? v3 : (e == 4) ? v4 : (e == 5) ? v5 :
                      (e == 6) ? v6 : (e == 7) ? v7 : v8;
      const float* wp = &wl[(kh * 9 + e) * 32];   // ((kh*3+kw)*3+ci)*32, e = kw*3+ci
      #pragma unroll
      for (int c8 = 0; c8 < 8; ++c8) {
        const float4 w4 = *(const float4*)(wp + c8 * 4);
        acc[c8 * 4 + 0] = fmaf(v, w4.x, acc[c8 * 4 + 0]);
        acc[c8 * 4 + 1] = fmaf(v, w4.y, acc[c8 * 4 + 1]);
        acc[c8 * 4 + 2] = fmaf(v, w4.z, acc[c8 * 4 + 2]);
        acc[c8 * 4 + 3] = fmaf(v, w4.w, acc[c8 * 4 + 3]);
      }
    }
  }

  const size_t g = ((size_t)bb * CH + oh) * CWID + ow;
  half8* dst = (half8*)(Fc + g * 32);
  #pragma unroll
  for (int q = 0; q < 4; ++q) {
    half8 o;
    #pragma unroll
    for (int e = 0; e < 8; ++e) o[e] = (_Float16)fmaxf(acc[q * 8 + e], 0.f);
    dst[q] = o;
  }
}

// ------- Kernel 2: f16 MFMA cost volume + soft-argmin (unchanged) -------
__global__ __launch_bounds__(256, 4)
void disparity_mfma_kernel(const _Float16* __restrict__ Fc, float* __restrict__ out) {
  __shared__ alignas(16) _Float16 raw[RAWP * 32];   // 12.3 KB (rows 179..191 = pad)
  __shared__ alignas(16) _Float16 flH[8 * 512];     // 8 tiles [16][32] f16
  __shared__ alignas(16) _Float16 gH[14 * 512];     // 14 tiles
  __shared__ alignas(16) float As[TW];
  __shared__ alignas(16) float Bs[GR];

  const int tid = threadIdx.x;
  const int w0  = blockIdx.x * TW;
  const int h   = blockIdx.y;
  const int bz  = blockIdx.z;

  // vertical bilinear params (half-pixel, clamped)
  const int hk = h >> 1;
  int r0, r1; float wv0;
  if (h & 1) { r0 = hk; r1 = (hk + 1 > CH - 1) ? CH - 1 : hk + 1; wv0 = 0.75f; }
  else       { r0 = (hk - 1 < 0) ? 0 : hk - 1; r1 = hk;           wv0 = 0.25f; }
  const half8 w0v = (half8)(_Float16)wv0;
  const half8 w1v = (half8)(_Float16)(1.0f - wv0);

  const int vbaseL = (w0 >> 1) + 639;  // fl raw region (t 0..65)
  const int vbaseR = (w0 >> 1) + 592;  // g raw region (t 66..178)

  char* const rawB = (char*)raw;

  // scalar row bases (hoisted 64-bit math)
  const char* const bL0 = (const char*)(Fc + ((size_t)bz * CH + r0) * CWID * 32);
  const char* const bL1 = (const char*)(Fc + ((size_t)bz * CH + r1) * CWID * 32);
  const char* const bR0 = (const char*)(Fc + ((size_t)(bz + 2) * CH + r0) * CWID * 32);
  const char* const bR1 = (const char*)(Fc + ((size_t)(bz + 2) * CH + r1) * CWID * 32);

  // ---- Phase 0: stage + vertical blend; 3 uniform tasks/thread (768 = 192*4) ----
  #pragma unroll
  for (int it = 0; it < 3; ++it) {
    const int task = tid + it * 256;
    const int t    = task >> 2;                     // 0..191 (179+ = pad)
    const int tc   = (t > RAWC - 1) ? RAWC - 1 : t; // clamp for address only
    const int c16  = task & 3;
    const bool isfl = tc < 66;
    int v = isfl ? (vbaseL + tc) : (vbaseR + tc - 66);  // in [592, 1280]
    v -= (v >= 640) ? 640 : 0;
    v -= (v >= 640) ? 640 : 0;                          // 1280 -> 0 (roll wrap)
    const char* p0 = isfl ? bL0 : bR0;
    const char* p1 = isfl ? bL1 : bR1;
    const int off = (v << 6) + (c16 << 4);
    const half8 a0 = *(const half8*)(p0 + off);
    const half8 a1 = *(const half8*)(p1 + off);
    const half8 vv = a0 * w0v + a1 * w1v;
    *(half8*)(rawB + t * 64 + ((c16 ^ (t & 3)) << 4)) = vv;
  }
  __syncthreads();

  // ---- Phase 1: horizontal blend + MFMA tiles + norms (same f16 values) ----
  const _Float16 h75 = (_Float16)0.75f, h25 = (_Float16)0.25f;
  auto row_body = [&](int row) {
    const bool isfl = row < TW;
    const int r  = isfl ? row : row - TW;
    const int uv = isfl ? (w0 + r) : (w0 - 95 + r);
    const int uact = uv < 0 ? uv + IMG_W : (uv >= IMG_W ? uv - IMG_W : uv);
    const int up = uv + IMG_W;                       // positive, same parity
    const int vm0 = (up - 1) >> 1;                   // branch-free taps
    int t0 = vm0 - (isfl ? vbaseL : (vbaseR - 66));
    int t1 = t0 + 1;
    if (uact == 0)         t0 = t1;   // left-edge clamp
    if (uact == IMG_W - 1) t1 = t0;   // right-edge clamp
    const _Float16 hw0 = (up & 1) ? h75 : h25;
    const _Float16 hw1 = (up & 1) ? h25 : h75;
    const half8 h0v = (half8)hw0;
    const half8 h1v = (half8)hw1;
    const char* r0p = rawB + t0 * 64;
    const char* r1p = rawB + t1 * 64;
    const int k0s = t0 & 3, k1s = t1 & 3;
    const int rr  = r & 15;
    char* dstB = (char*)(isfl ? flH : gH) + (r >> 4) * 1024 + rr * 64;
    float s = 0.f;
    #pragma unroll
    for (int c16 = 0; c16 < 4; ++c16) {
      const half8 a = *(const half8*)(r0p + ((c16 ^ k0s) << 4));
      const half8 b = *(const half8*)(r1p + ((c16 ^ k1s) << 4));
      const half8 v = a * h0v + b * h1v;
      #pragma unroll
      for (int e = 0; e < 4; ++e) {
        h2 pe = {v[2 * e], v[2 * e + 1]};
#if __has_builtin(__builtin_amdgcn_fdot2)
        s = __builtin_amdgcn_fdot2(pe, pe, s, false);
#else
        s += (float)pe[0] * (float)pe[0] + (float)pe[1] * (float)pe[1];
#endif
      }
      *(half8*)(dstB + ((c16 ^ (rr & 3)) << 4)) = v;
    }
    if (isfl) As[r] = s; else Bs[r] = s;
  };
  row_body(tid);
  if (tid < TW + GR - 256) row_body(tid + 256);
  __syncthreads();

  // ---- Phase 2: MFMA band + per-pixel soft-argmin ----
  const int lane = tid & 63;
  const int wid  = tid >> 6;
  const int n  = lane & 15;   // fl row within tile (C col)
  const int gq = lane >> 4;   // k-slice / C row group
  const int foffB = n * 64 + ((gq ^ (n & 3)) << 4);
  const int bpaddr = (lane ^ 32) << 2;   // shared xor-32 bpermute address

  #pragma unroll
  for (int pp = 0; pp < 2; ++pp) {
    const int p = wid * 2 + pp;          // i-tile 0..7
    const half8 bfrag = *(const half8*)((const char*)flH + p * 1024 + foffB);
    f32x4 acc[7];
    #pragma unroll
    for (int dq = 0; dq < 7; ++dq) {
      const half8 afrag = *(const half8*)((const char*)gH + (p + dq) * 1024 + foffB);
      f32x4 z = {0.f, 0.f, 0.f, 0.f};
      acc[dq] = __builtin_amdgcn_mfma_f32_16x16x32_f16(afrag, bfrag, z, 0, 0, 0);
    }

    // pass 1: cost + min/max (invalid cells -> +3e38 so pass 2 is mask-free;
    // min/max paired for v_min3/v_max3 fusion — exact, min/max associative)
    const float Ai = As[p * 16 + n];
    float cv[7][4];
    float mn = 3.0e38f, mx = -3.0e38f;
    #pragma unroll
    for (int dq = 0; dq < 7; ++dq) {
      const f32x4 b4 = *(const f32x4*)(&Bs[(p + dq) * 16 + gq * 4]);
      float cm[4], cx[4];
      #pragma unroll
      for (int rg = 0; rg < 4; ++rg) {
        const int m = gq * 4 + rg;
        const float cc = fmaf(-2.f, acc[dq][rg], Ai + b4[rg]);
        const bool valid = (dq != 0 || m >= n) && (dq != 6 || m < n);
        cm[rg] = valid ? cc : 3.0e38f;
        cx[rg] = valid ? cc : -3.0e38f;
        cv[dq][rg] = cm[rg];
      }
      mn = fminf(mn, fminf(fminf(cm[0], cm[1]), fminf(cm[2], cm[3])));
      mx = fmaxf(mx, fmaxf(fmaxf(cx[0], cx[1]), fmaxf(cx[2], cx[3])));
    }
    mn = fminf(mn, swz16(mn));
    mx = fmaxf(mx, swz16(mx));
    mn = fminf(mn, bperm(bpaddr, mn));
    mx = fmaxf(mx, bperm(bpaddr, mx));

    // pass 2: mask-free softmax accumulation, 2 accumulator pairs for ILP
    const float ralpha = 177.0f * 1.4426950408889634f * fastrcp(mx);
    const float na   = -ralpha;
    const float base = ralpha * mn;
    float sw0 = 0.f, sdw0 = 0.f, sw1 = 0.f, sdw1 = 0.f;
    #pragma unroll
    for (int dq = 0; dq < 7; ++dq) {
      #pragma unroll
      for (int rg = 0; rg < 4; ++rg) {
        const int m = gq * 4 + rg;
        const float wgt = fastexp2(fmaf(na, cv[dq][rg], base));  // 0 for masked
        const float kf = (float)(95 - (dq * 16 + m - n));        // d = 95 - k
        if (rg & 2) { sw1 += wgt; sdw1 = fmaf(kf, wgt, sdw1); }
        else        { sw0 += wgt; sdw0 = fmaf(kf, wgt, sdw0); }
      }
    }
    float sw = sw0 + sw1, sdw = sdw0 + sdw1;
    sw  += swz16(sw);
    sdw += swz16(sdw);
    sw  += bperm(bpaddr, sw);
    sdw += bperm(bpaddr, sdw);
    if (gq == 0)
      out[((size_t)bz * IMG_H + h) * IMG_W + w0 + p * 16 + n] = sdw * fastrcp(sw);
  }
}

extern "C" void kernel_launch(void* const* d_in, const int* in_sizes, int n_in,
                              void* d_out, int out_size, void* d_ws, size_t ws_size,
                              hipStream_t stream) {
  (void)in_sizes; (void)n_in; (void)out_size; (void)ws_size;
  const float* xl   = (const float*)d_in[0];
  const float* xr   = (const float*)d_in[1];
  const float* Wt   = (const float*)d_in[2];
  const float* bias = (const float*)d_in[3];
  _Float16* Fc = (_Float16*)d_ws;   // conv features [4,192,640,32] f16 = 31.5 MB
  float* out = (float*)d_out;       // [2,384,1280] f32

  hipLaunchKernelGGL(conv_relu_kernel, dim3(5, 96, 4), dim3(256), 0, stream,
                     xl, xr, Wt, bias, Fc);
  hipLaunchKernelGGL(disparity_mfma_kernel, dim3(IMG_W / TW, IMG_H, 2), dim3(256), 0, stream,
                     Fc, out);
}

// Round 9
// 78.679 us; speedup vs baseline: 7.0030x; 2.3244x over previous
//
#include <hip/hip_runtime.h>
#include <cstddef>

typedef _Float16 h2    __attribute__((ext_vector_type(2)));
typedef _Float16 half8 __attribute__((ext_vector_type(8)));
typedef float    f32x4 __attribute__((ext_vector_type(4)));

#define CH    192
#define CWID  640
#define IMG_H 384
#define IMG_W 1280
#define TW    128
#define GR    224      // g rows staged
#define RAWC  179      // 66 fl cols + 113 g cols (+pad to 192)
#define RAWP  192

__device__ __forceinline__ float fastrcp(float x) {
#if __has_builtin(__builtin_amdgcn_rcpf)
  return __builtin_amdgcn_rcpf(x);
#else
  return 1.0f / x;
#endif
}
__device__ __forceinline__ float fastexp2(float x) {
#if __has_builtin(__builtin_amdgcn_exp2f)
  return __builtin_amdgcn_exp2f(x);
#else
  return exp2f(x);
#endif
}
// xor-16 within 32-lane halves: BitMode offset = (16<<10)|0x1F
__device__ __forceinline__ float swz16(float x) {
  return __uint_as_float((unsigned)__builtin_amdgcn_ds_swizzle((int)__float_as_uint(x), 0x401F));
}
__device__ __forceinline__ float bperm(int addr, float x) {
  return __uint_as_float((unsigned)__builtin_amdgcn_ds_bpermute(addr, (int)__float_as_uint(x)));
}

// ---------------- Kernel 1: 3x3 stride-2 SAME conv + bias + ReLU -> f16 ----------------
// VERBATIM R4 conv (measured ~18us, no scratch). R6/R7/R8 restructurings (vector-load
// cluster / launch-bounds cap / named-scalar variant) all triggered allocator scratch
// demotion of acc[32] (252MB scratch writes, 122-507us). Do not restructure this kernel.
__global__ __launch_bounds__(256)
void conv_relu_kernel(const float* __restrict__ xl, const float* __restrict__ xr,
                      const float* __restrict__ Wt, const float* __restrict__ bias,
                      _Float16* __restrict__ Fc) {
  __shared__ float wl[864];
  __shared__ float bl[32];
  const int tid = threadIdx.x;
  for (int t = tid; t < 864; t += 256) wl[t] = Wt[t];
  if (tid < 32) bl[tid] = bias[tid];
  __syncthreads();

  const int g  = blockIdx.x * 256 + tid;   // [0, 4*192*640)
  const int ow = g % CWID;
  const int t2 = g / CWID;
  const int oh = t2 % CH;
  const int bb = t2 / CH;
  const float* src = (bb < 2) ? (xl + (size_t)bb * IMG_H * IMG_W * 3)
                              : (xr + (size_t)(bb - 2) * IMG_H * IMG_W * 3);
  float acc[32];
  #pragma unroll
  for (int c = 0; c < 32; ++c) acc[c] = bl[c];

  #pragma unroll
  for (int kh = 0; kh < 3; ++kh) {
    const int ir = oh * 2 + kh;
    if (ir >= IMG_H) continue;
    #pragma unroll
    for (int kw = 0; kw < 3; ++kw) {
      const int ic = ow * 2 + kw;
      if (ic >= IMG_W) continue;
      const float* px = src + ((size_t)ir * IMG_W + ic) * 3;
      #pragma unroll
      for (int ci = 0; ci < 3; ++ci) {
        const float v = px[ci];
        const float* wp = &wl[((kh * 3 + kw) * 3 + ci) * 32];
        #pragma unroll
        for (int c8 = 0; c8 < 8; ++c8) {
          const float4 w4 = *(const float4*)(wp + c8 * 4);
          acc[c8 * 4 + 0] = fmaf(v, w4.x, acc[c8 * 4 + 0]);
          acc[c8 * 4 + 1] = fmaf(v, w4.y, acc[c8 * 4 + 1]);
          acc[c8 * 4 + 2] = fmaf(v, w4.z, acc[c8 * 4 + 2]);
          acc[c8 * 4 + 3] = fmaf(v, w4.w, acc[c8 * 4 + 3]);
        }
      }
    }
  }
  // relu + pack to f16 (RNE via scalar cvt), 4x 16B stores
  _Float16 hv[32];
  #pragma unroll
  for (int c = 0; c < 32; ++c) hv[c] = (_Float16)fmaxf(acc[c], 0.f);
  half8* dst = (half8*)(Fc + (size_t)g * 32);
  #pragma unroll
  for (int q = 0; q < 4; ++q) {
    half8 o;
    #pragma unroll
    for (int e = 0; e < 8; ++e) o[e] = hv[q * 8 + e];
    dst[q] = o;
  }
}

// ------- Kernel 2: f16 MFMA cost volume + soft-argmin (unchanged) -------
__global__ __launch_bounds__(256, 4)
void disparity_mfma_kernel(const _Float16* __restrict__ Fc, float* __restrict__ out) {
  __shared__ alignas(16) _Float16 raw[RAWP * 32];   // 12.3 KB (rows 179..191 = pad)
  __shared__ alignas(16) _Float16 flH[8 * 512];     // 8 tiles [16][32] f16
  __shared__ alignas(16) _Float16 gH[14 * 512];     // 14 tiles
  __shared__ alignas(16) float As[TW];
  __shared__ alignas(16) float Bs[GR];

  const int tid = threadIdx.x;
  const int w0  = blockIdx.x * TW;
  const int h   = blockIdx.y;
  const int bz  = blockIdx.z;

  // vertical bilinear params (half-pixel, clamped)
  const int hk = h >> 1;
  int r0, r1; float wv0;
  if (h & 1) { r0 = hk; r1 = (hk + 1 > CH - 1) ? CH - 1 : hk + 1; wv0 = 0.75f; }
  else       { r0 = (hk - 1 < 0) ? 0 : hk - 1; r1 = hk;           wv0 = 0.25f; }
  const half8 w0v = (half8)(_Float16)wv0;
  const half8 w1v = (half8)(_Float16)(1.0f - wv0);

  const int vbaseL = (w0 >> 1) + 639;  // fl raw region (t 0..65)
  const int vbaseR = (w0 >> 1) + 592;  // g raw region (t 66..178)

  char* const rawB = (char*)raw;

  // scalar row bases (hoisted 64-bit math)
  const char* const bL0 = (const char*)(Fc + ((size_t)bz * CH + r0) * CWID * 32);
  const char* const bL1 = (const char*)(Fc + ((size_t)bz * CH + r1) * CWID * 32);
  const char* const bR0 = (const char*)(Fc + ((size_t)(bz + 2) * CH + r0) * CWID * 32);
  const char* const bR1 = (const char*)(Fc + ((size_t)(bz + 2) * CH + r1) * CWID * 32);

  // ---- Phase 0: stage + vertical blend; 3 uniform tasks/thread (768 = 192*4) ----
  #pragma unroll
  for (int it = 0; it < 3; ++it) {
    const int task = tid + it * 256;
    const int t    = task >> 2;                     // 0..191 (179+ = pad)
    const int tc   = (t > RAWC - 1) ? RAWC - 1 : t; // clamp for address only
    const int c16  = task & 3;
    const bool isfl = tc < 66;
    int v = isfl ? (vbaseL + tc) : (vbaseR + tc - 66);  // in [592, 1280]
    v -= (v >= 640) ? 640 : 0;
    v -= (v >= 640) ? 640 : 0;                          // 1280 -> 0 (roll wrap)
    const char* p0 = isfl ? bL0 : bR0;
    const char* p1 = isfl ? bL1 : bR1;
    const int off = (v << 6) + (c16 << 4);
    const half8 a0 = *(const half8*)(p0 + off);
    const half8 a1 = *(const half8*)(p1 + off);
    const half8 vv = a0 * w0v + a1 * w1v;
    *(half8*)(rawB + t * 64 + ((c16 ^ (t & 3)) << 4)) = vv;
  }
  __syncthreads();

  // ---- Phase 1: horizontal blend + MFMA tiles + norms (same f16 values) ----
  const _Float16 h75 = (_Float16)0.75f, h25 = (_Float16)0.25f;
  auto row_body = [&](int row) {
    const bool isfl = row < TW;
    const int r  = isfl ? row : row - TW;
    const int uv = isfl ? (w0 + r) : (w0 - 95 + r);
    const int uact = uv < 0 ? uv + IMG_W : (uv >= IMG_W ? uv - IMG_W : uv);
    const int up = uv + IMG_W;                       // positive, same parity
    const int vm0 = (up - 1) >> 1;                   // branch-free taps
    int t0 = vm0 - (isfl ? vbaseL : (vbaseR - 66));
    int t1 = t0 + 1;
    if (uact == 0)         t0 = t1;   // left-edge clamp
    if (uact == IMG_W - 1) t1 = t0;   // right-edge clamp
    const _Float16 hw0 = (up & 1) ? h75 : h25;
    const _Float16 hw1 = (up & 1) ? h25 : h75;
    const half8 h0v = (half8)hw0;
    const half8 h1v = (half8)hw1;
    const char* r0p = rawB + t0 * 64;
    const char* r1p = rawB + t1 * 64;
    const int k0s = t0 & 3, k1s = t1 & 3;
    const int rr  = r & 15;
    char* dstB = (char*)(isfl ? flH : gH) + (r >> 4) * 1024 + rr * 64;
    float s = 0.f;
    #pragma unroll
    for (int c16 = 0; c16 < 4; ++c16) {
      const half8 a = *(const half8*)(r0p + ((c16 ^ k0s) << 4));
      const half8 b = *(const half8*)(r1p + ((c16 ^ k1s) << 4));
      const half8 v = a * h0v + b * h1v;
      #pragma unroll
      for (int e = 0; e < 4; ++e) {
        h2 pe = {v[2 * e], v[2 * e + 1]};
#if __has_builtin(__builtin_amdgcn_fdot2)
        s = __builtin_amdgcn_fdot2(pe, pe, s, false);
#else
        s += (float)pe[0] * (float)pe[0] + (float)pe[1] * (float)pe[1];
#endif
      }
      *(half8*)(dstB + ((c16 ^ (rr & 3)) << 4)) = v;
    }
    if (isfl) As[r] = s; else Bs[r] = s;
  };
  row_body(tid);
  if (tid < TW + GR - 256) row_body(tid + 256);
  __syncthreads();

  // ---- Phase 2: MFMA band + per-pixel soft-argmin ----
  const int lane = tid & 63;
  const int wid  = tid >> 6;
  const int n  = lane & 15;   // fl row within tile (C col)
  const int gq = lane >> 4;   // k-slice / C row group
  const int foffB = n * 64 + ((gq ^ (n & 3)) << 4);
  const int bpaddr = (lane ^ 32) << 2;   // shared xor-32 bpermute address

  #pragma unroll
  for (int pp = 0; pp < 2; ++pp) {
    const int p = wid * 2 + pp;          // i-tile 0..7
    const half8 bfrag = *(const half8*)((const char*)flH + p * 1024 + foffB);
    f32x4 acc[7];
    #pragma unroll
    for (int dq = 0; dq < 7; ++dq) {
      const half8 afrag = *(const half8*)((const char*)gH + (p + dq) * 1024 + foffB);
      f32x4 z = {0.f, 0.f, 0.f, 0.f};
      acc[dq] = __builtin_amdgcn_mfma_f32_16x16x32_f16(afrag, bfrag, z, 0, 0, 0);
    }

    // pass 1: cost + min/max (invalid cells -> +3e38 so pass 2 is mask-free;
    // min/max paired for v_min3/v_max3 fusion — exact, min/max associative)
    const float Ai = As[p * 16 + n];
    float cv[7][4];
    float mn = 3.0e38f, mx = -3.0e38f;
    #pragma unroll
    for (int dq = 0; dq < 7; ++dq) {
      const f32x4 b4 = *(const f32x4*)(&Bs[(p + dq) * 16 + gq * 4]);
      float cm[4], cx[4];
      #pragma unroll
      for (int rg = 0; rg < 4; ++rg) {
        const int m = gq * 4 + rg;
        const float cc = fmaf(-2.f, acc[dq][rg], Ai + b4[rg]);
        const bool valid = (dq != 0 || m >= n) && (dq != 6 || m < n);
        cm[rg] = valid ? cc : 3.0e38f;
        cx[rg] = valid ? cc : -3.0e38f;
        cv[dq][rg] = cm[rg];
      }
      mn = fminf(mn, fminf(fminf(cm[0], cm[1]), fminf(cm[2], cm[3])));
      mx = fmaxf(mx, fmaxf(fmaxf(cx[0], cx[1]), fmaxf(cx[2], cx[3])));
    }
    mn = fminf(mn, swz16(mn));
    mx = fmaxf(mx, swz16(mx));
    mn = fminf(mn, bperm(bpaddr, mn));
    mx = fmaxf(mx, bperm(bpaddr, mx));

    // pass 2: mask-free softmax accumulation, 2 accumulator pairs for ILP
    const float ralpha = 177.0f * 1.4426950408889634f * fastrcp(mx);
    const float na   = -ralpha;
    const float base = ralpha * mn;
    float sw0 = 0.f, sdw0 = 0.f, sw1 = 0.f, sdw1 = 0.f;
    #pragma unroll
    for (int dq = 0; dq < 7; ++dq) {
      #pragma unroll
      for (int rg = 0; rg < 4; ++rg) {
        const int m = gq * 4 + rg;
        const float wgt = fastexp2(fmaf(na, cv[dq][rg], base));  // 0 for masked
        const float kf = (float)(95 - (dq * 16 + m - n));        // d = 95 - k
        if (rg & 2) { sw1 += wgt; sdw1 = fmaf(kf, wgt, sdw1); }
        else        { sw0 += wgt; sdw0 = fmaf(kf, wgt, sdw0); }
      }
    }
    float sw = sw0 + sw1, sdw = sdw0 + sdw1;
    sw  += swz16(sw);
    sdw += swz16(sdw);
    sw  += bperm(bpaddr, sw);
    sdw += bperm(bpaddr, sdw);
    if (gq == 0)
      out[((size_t)bz * IMG_H + h) * IMG_W + w0 + p * 16 + n] = sdw * fastrcp(sw);
  }
}

extern "C" void kernel_launch(void* const* d_in, const int* in_sizes, int n_in,
                              void* d_out, int out_size, void* d_ws, size_t ws_size,
                              hipStream_t stream) {
  (void)in_sizes; (void)n_in; (void)out_size; (void)ws_size;
  const float* xl   = (const float*)d_in[0];
  const float* xr   = (const float*)d_in[1];
  const float* Wt   = (const float*)d_in[2];
  const float* bias = (const float*)d_in[3];
  _Float16* Fc = (_Float16*)d_ws;   // conv features [4,192,640,32] f16 = 31.5 MB
  float* out = (float*)d_out;       // [2,384,1280] f32

  hipLaunchKernelGGL(conv_relu_kernel, dim3(1920), dim3(256), 0, stream,
                     xl, xr, Wt, bias, Fc);
  hipLaunchKernelGGL(disparity_mfma_kernel, dim3(IMG_W / TW, IMG_H, 2), dim3(256), 0, stream,
                     Fc, out);
}

// Round 10
// 77.069 us; speedup vs baseline: 7.1493x; 1.0209x over previous
//
#include <hip/hip_runtime.h>
#include <cstddef>

typedef _Float16 h2    __attribute__((ext_vector_type(2)));
typedef _Float16 half8 __attribute__((ext_vector_type(8)));
typedef float    f32x4 __attribute__((ext_vector_type(4)));
typedef float    f32x2 __attribute__((ext_vector_type(2)));

#define CH    192
#define CWID  640
#define IMG_H 384
#define IMG_W 1280
#define TW    128
#define GR    224      // g rows staged
#define RAWC  179      // 66 fl cols + 113 g cols (+pad to 192)
#define RAWP  192

__device__ __forceinline__ float fastrcp(float x) {
#if __has_builtin(__builtin_amdgcn_rcpf)
  return __builtin_amdgcn_rcpf(x);
#else
  return 1.0f / x;
#endif
}
__device__ __forceinline__ float fastexp2(float x) {
#if __has_builtin(__builtin_amdgcn_exp2f)
  return __builtin_amdgcn_exp2f(x);
#else
  return exp2f(x);
#endif
}
// xor-16 within 32-lane halves: BitMode offset = (16<<10)|0x1F
__device__ __forceinline__ float swz16(float x) {
  return __uint_as_float((unsigned)__builtin_amdgcn_ds_swizzle((int)__float_as_uint(x), 0x401F));
}
__device__ __forceinline__ float bperm(int addr, float x) {
  return __uint_as_float((unsigned)__builtin_amdgcn_ds_bpermute(addr, (int)__float_as_uint(x)));
}
// CDNA VOP3P packed-f32 (dual f32 per inst) — hipcc never auto-forms these.
__device__ __forceinline__ f32x2 pkadd(f32x2 a, f32x2 b) {
  f32x2 d; asm("v_pk_add_f32 %0, %1, %2" : "=v"(d) : "v"(a), "v"(b)); return d;
}
__device__ __forceinline__ f32x2 pkfma(f32x2 a, f32x2 b, f32x2 c) {
  f32x2 d; asm("v_pk_fma_f32 %0, %1, %2, %3" : "=v"(d) : "v"(a), "v"(b), "v"(c)); return d;
}
__device__ __forceinline__ float min3f(float a, float b, float c) {
  float d; asm("v_min3_f32 %0, %1, %2, %3" : "=v"(d) : "v"(a), "v"(b), "v"(c)); return d;
}
__device__ __forceinline__ float max3f(float a, float b, float c) {
  float d; asm("v_max3_f32 %0, %1, %2, %3" : "=v"(d) : "v"(a), "v"(b), "v"(c)); return d;
}
__device__ __forceinline__ f32x2 lo2(f32x4 v) { f32x2 r; r.x = v.x; r.y = v.y; return r; }
__device__ __forceinline__ f32x2 hi2(f32x4 v) { f32x2 r; r.x = v.z; r.y = v.w; return r; }

// ---------------- Kernel 1: 3x3 stride-2 SAME conv + bias + ReLU -> f16 ----------------
// VERBATIM R4 conv (measured ~18us, no scratch). R6/R7/R8 restructurings all triggered
// allocator scratch demotion of acc[32] (252MB scratch writes). Do not restructure.
__global__ __launch_bounds__(256)
void conv_relu_kernel(const float* __restrict__ xl, const float* __restrict__ xr,
                      const float* __restrict__ Wt, const float* __restrict__ bias,
                      _Float16* __restrict__ Fc) {
  __shared__ float wl[864];
  __shared__ float bl[32];
  const int tid = threadIdx.x;
  for (int t = tid; t < 864; t += 256) wl[t] = Wt[t];
  if (tid < 32) bl[tid] = bias[tid];
  __syncthreads();

  const int g  = blockIdx.x * 256 + tid;   // [0, 4*192*640)
  const int ow = g % CWID;
  const int t2 = g / CWID;
  const int oh = t2 % CH;
  const int bb = t2 / CH;
  const float* src = (bb < 2) ? (xl + (size_t)bb * IMG_H * IMG_W * 3)
                              : (xr + (size_t)(bb - 2) * IMG_H * IMG_W * 3);
  float acc[32];
  #pragma unroll
  for (int c = 0; c < 32; ++c) acc[c] = bl[c];

  #pragma unroll
  for (int kh = 0; kh < 3; ++kh) {
    const int ir = oh * 2 + kh;
    if (ir >= IMG_H) continue;
    #pragma unroll
    for (int kw = 0; kw < 3; ++kw) {
      const int ic = ow * 2 + kw;
      if (ic >= IMG_W) continue;
      const float* px = src + ((size_t)ir * IMG_W + ic) * 3;
      #pragma unroll
      for (int ci = 0; ci < 3; ++ci) {
        const float v = px[ci];
        const float* wp = &wl[((kh * 3 + kw) * 3 + ci) * 32];
        #pragma unroll
        for (int c8 = 0; c8 < 8; ++c8) {
          const float4 w4 = *(const float4*)(wp + c8 * 4);
          acc[c8 * 4 + 0] = fmaf(v, w4.x, acc[c8 * 4 + 0]);
          acc[c8 * 4 + 1] = fmaf(v, w4.y, acc[c8 * 4 + 1]);
          acc[c8 * 4 + 2] = fmaf(v, w4.z, acc[c8 * 4 + 2]);
          acc[c8 * 4 + 3] = fmaf(v, w4.w, acc[c8 * 4 + 3]);
        }
      }
    }
  }
  _Float16 hv[32];
  #pragma unroll
  for (int c = 0; c < 32; ++c) hv[c] = (_Float16)fmaxf(acc[c], 0.f);
  half8* dst = (half8*)(Fc + (size_t)g * 32);
  #pragma unroll
  for (int q = 0; q < 4; ++q) {
    half8 o;
    #pragma unroll
    for (int e = 0; e < 8; ++e) o[e] = hv[q * 8 + e];
    dst[q] = o;
  }
}

// ------- Kernel 2: f16 MFMA cost volume + soft-argmin -------
// raw staged in 2 channel-halves (LDS 30080B -> 5 blocks/CU); epilogue uses packed
// f32 (v_pk_add/fma_f32) + v_min3/v_max3, and skw (literal-K) replaces per-cell kf.
__global__ __launch_bounds__(256, 4)
void disparity_mfma_kernel(const _Float16* __restrict__ Fc, float* __restrict__ out) {
  __shared__ alignas(16) _Float16 raw[RAWP * 16];   // 6 KB: 192 rows x 32B (2 chunks)
  __shared__ alignas(16) _Float16 flH[8 * 512];     // 8 tiles [16][32] f16
  __shared__ alignas(16) _Float16 gH[14 * 512];     // 14 tiles
  __shared__ alignas(16) float As[TW];
  __shared__ alignas(16) float Bs[GR];

  const int tid = threadIdx.x;
  const int w0  = blockIdx.x * TW;
  const int h   = blockIdx.y;
  const int bz  = blockIdx.z;

  // vertical bilinear params (half-pixel, clamped)
  const int hk = h >> 1;
  int r0, r1; float wv0;
  if (h & 1) { r0 = hk; r1 = (hk + 1 > CH - 1) ? CH - 1 : hk + 1; wv0 = 0.75f; }
  else       { r0 = (hk - 1 < 0) ? 0 : hk - 1; r1 = hk;           wv0 = 0.25f; }
  const half8 w0v = (half8)(_Float16)wv0;
  const half8 w1v = (half8)(_Float16)(1.0f - wv0);

  const int vbaseL = (w0 >> 1) + 639;  // fl raw region (t 0..65)
  const int vbaseR = (w0 >> 1) + 592;  // g raw region (t 66..178)

  char* const rawB = (char*)raw;

  // scalar row bases (hoisted 64-bit math)
  const char* const bL0 = (const char*)(Fc + ((size_t)bz * CH + r0) * CWID * 32);
  const char* const bL1 = (const char*)(Fc + ((size_t)bz * CH + r1) * CWID * 32);
  const char* const bR0 = (const char*)(Fc + ((size_t)(bz + 2) * CH + r0) * CWID * 32);
  const char* const bR1 = (const char*)(Fc + ((size_t)(bz + 2) * CH + r1) * CWID * 32);

  // ---- precompute phase-1 row params for row A = tid and row B = tid+256 ----
  const _Float16 h75 = (_Float16)0.75f, h25 = (_Float16)0.25f;
  int a_r0off, a_s0, a_r1off, a_s1, a_swz; half8 a_h0, a_h1; char* a_dst;
  int b_r0off, b_s0, b_r1off, b_s1, b_swz; half8 b_h0, b_h1; char* b_dst;
  {
    const int row = tid;
    const bool isfl = row < TW;
    const int r  = isfl ? row : row - TW;
    const int uv = isfl ? (w0 + r) : (w0 - 95 + r);
    const int uact = uv < 0 ? uv + IMG_W : (uv >= IMG_W ? uv - IMG_W : uv);
    const int up = uv + IMG_W;
    const int vm0 = (up - 1) >> 1;
    int t0 = vm0 - (isfl ? vbaseL : (vbaseR - 66));
    int t1 = t0 + 1;
    if (uact == 0)         t0 = t1;
    if (uact == IMG_W - 1) t1 = t0;
    a_h0 = (half8)((up & 1) ? h75 : h25);
    a_h1 = (half8)((up & 1) ? h25 : h75);
    a_r0off = t0 * 32; a_s0 = (t0 & 1) << 4;
    a_r1off = t1 * 32; a_s1 = (t1 & 1) << 4;
    a_swz = r & 3;
    a_dst = (char*)(isfl ? flH : gH) + (r >> 4) * 1024 + (r & 15) * 64;
  }
  {
    const int row = tid + 256;   // always a g row (256..351) when used
    const int r  = row - TW;
    const int uv = w0 - 95 + r;
    const int uact = uv < 0 ? uv + IMG_W : (uv >= IMG_W ? uv - IMG_W : uv);
    const int up = uv + IMG_W;
    const int vm0 = (up - 1) >> 1;
    int t0 = vm0 - (vbaseR - 66);
    int t1 = t0 + 1;
    if (uact == 0)         t0 = t1;
    if (uact == IMG_W - 1) t1 = t0;
    b_h0 = (half8)((up & 1) ? h75 : h25);
    b_h1 = (half8)((up & 1) ? h25 : h75);
    b_r0off = t0 * 32; b_s0 = (t0 & 1) << 4;
    b_r1off = t1 * 32; b_s1 = (t1 & 1) << 4;
    b_swz = r & 3;
    b_dst = (char*)gH + (r >> 4) * 1024 + (r & 15) * 64;
  }

  float sA = 0.f, sB = 0.f;
  #pragma unroll
  for (int half = 0; half < 2; ++half) {
    // ---- Phase 0: stage 2 channel-chunks of this half + vertical blend ----
    #pragma unroll
    for (int it = 0; it < 2; ++it) {
      const int task = tid + it * 256;     // 384 tasks (192 t x 2 cpos)
      if (it == 0 || tid < 128) {
        const int t    = task >> 1;
        const int cpos = task & 1;
        const int tc   = (t > RAWC - 1) ? RAWC - 1 : t;
        const bool isfl = tc < 66;
        int v = isfl ? (vbaseL + tc) : (vbaseR + tc - 66);   // in [592, 1280]
        v -= (v >= 640) ? 640 : 0;
        v -= (v >= 640) ? 640 : 0;                            // 1280 -> 0 (roll wrap)
        const char* p0 = isfl ? bL0 : bR0;
        const char* p1 = isfl ? bL1 : bR1;
        const int off = (v << 6) + ((half * 2 + cpos) << 4);
        const half8 a0 = *(const half8*)(p0 + off);
        const half8 a1 = *(const half8*)(p1 + off);
        const half8 vv = a0 * w0v + a1 * w1v;
        *(half8*)(rawB + t * 32 + ((cpos ^ (t & 1)) << 4)) = vv;
      }
    }
    __syncthreads();

    // ---- Phase 1: horizontal blend + tiles + norm partials (this half) ----
    #pragma unroll
    for (int cpos = 0; cpos < 2; ++cpos) {
      const int c16 = half * 2 + cpos;
      const int cb  = cpos << 4;
      {
        const half8 a = *(const half8*)(rawB + a_r0off + (cb ^ a_s0));
        const half8 b = *(const half8*)(rawB + a_r1off + (cb ^ a_s1));
        const half8 v = a * a_h0 + b * a_h1;
        #pragma unroll
        for (int e = 0; e < 4; ++e) {
          h2 pe = {v[2 * e], v[2 * e + 1]};
#if __has_builtin(__builtin_amdgcn_fdot2)
          sA = __builtin_amdgcn_fdot2(pe, pe, sA, false);
#else
          sA += (float)pe[0] * (float)pe[0] + (float)pe[1] * (float)pe[1];
#endif
        }
        *(half8*)(a_dst + ((c16 ^ a_swz) << 4)) = v;
      }
      if (tid < TW + GR - 256) {
        const half8 a = *(const half8*)(rawB + b_r0off + (cb ^ b_s0));
        const half8 b = *(const half8*)(rawB + b_r1off + (cb ^ b_s1));
        const half8 v = a * b_h0 + b * b_h1;
        #pragma unroll
        for (int e = 0; e < 4; ++e) {
          h2 pe = {v[2 * e], v[2 * e + 1]};
#if __has_builtin(__builtin_amdgcn_fdot2)
          sB = __builtin_amdgcn_fdot2(pe, pe, sB, false);
#else
          sB += (float)pe[0] * (float)pe[0] + (float)pe[1] * (float)pe[1];
#endif
        }
        *(half8*)(b_dst + ((c16 ^ b_swz) << 4)) = v;
      }
    }
    __syncthreads();   // raw reads done before next half overwrites
  }
  if (tid < TW) As[tid] = sA; else Bs[tid - TW] = sA;
  if (tid < TW + GR - 256) Bs[tid + 256 - TW] = sB;
  __syncthreads();

  // ---- Phase 2: MFMA band + per-pixel soft-argmin ----
  const int lane = tid & 63;
  const int wid  = tid >> 6;
  const int n  = lane & 15;   // fl row within tile (C col)
  const int gq = lane >> 4;   // k-slice / C row group
  const int foffB = n * 64 + ((gq ^ (n & 3)) << 4);
  const int bpaddr = (lane ^ 32) << 2;   // shared xor-32 bpermute address
  const float Cbase = (float)(95 - 4 * gq + n);   // kf = Cbase - (16*dq + rg)

  #pragma unroll
  for (int pp = 0; pp < 2; ++pp) {
    const int p = wid * 2 + pp;          // i-tile 0..7
    const half8 bfrag = *(const half8*)((const char*)flH + p * 1024 + foffB);
    f32x4 acc[7];
    #pragma unroll
    for (int dq = 0; dq < 7; ++dq) {
      const half8 afrag = *(const half8*)((const char*)gH + (p + dq) * 1024 + foffB);
      f32x4 z = {0.f, 0.f, 0.f, 0.f};
      acc[dq] = __builtin_amdgcn_mfma_f32_16x16x32_f16(afrag, bfrag, z, 0, 0, 0);
    }

    // pass 1 (packed): cc = pk_fma(-2, acc, Ai + Bj); invalid cells (dq 0/6 only)
    // -> +3e38 so pass 2 is mask-free; min/max via v_min3/v_max3 (exact).
    const float Ai = As[p * 16 + n];
    f32x2 AiP; AiP.x = Ai; AiP.y = Ai;
    f32x2 m2P; m2P.x = -2.f; m2P.y = -2.f;
    float mn = 3.0e38f, mx = -3.0e38f;
    #pragma unroll
    for (int dq = 0; dq < 7; ++dq) {
      const f32x4 b4 = *(const f32x4*)(&Bs[(p + dq) * 16 + gq * 4]);
      f32x2 c01 = pkfma(m2P, lo2(acc[dq]), pkadd(AiP, lo2(b4)));
      f32x2 c23 = pkfma(m2P, hi2(acc[dq]), pkadd(AiP, hi2(b4)));
      if (dq == 0 || dq == 6) {
        float e0 = c01.x, e1 = c01.y, e2 = c23.x, e3 = c23.y;
        const bool v0 = (dq == 0) ? (gq * 4 + 0 >= n) : (gq * 4 + 0 < n);
        const bool v1 = (dq == 0) ? (gq * 4 + 1 >= n) : (gq * 4 + 1 < n);
        const bool v2 = (dq == 0) ? (gq * 4 + 2 >= n) : (gq * 4 + 2 < n);
        const bool v3 = (dq == 0) ? (gq * 4 + 3 >= n) : (gq * 4 + 3 < n);
        mx = max3f(mx, v0 ? e0 : -3.0e38f, v1 ? e1 : -3.0e38f);
        mx = max3f(mx, v2 ? e2 : -3.0e38f, v3 ? e3 : -3.0e38f);
        c01.x = v0 ? e0 : 3.0e38f;  c01.y = v1 ? e1 : 3.0e38f;
        c23.x = v2 ? e2 : 3.0e38f;  c23.y = v3 ? e3 : 3.0e38f;
        mn = min3f(mn, c01.x, c01.y);
        mn = min3f(mn, c23.x, c23.y);
      } else {
        mn = min3f(mn, c01.x, c01.y);
        mn = min3f(mn, c23.x, c23.y);
        mx = max3f(mx, c01.x, c01.y);
        mx = max3f(mx, c23.x, c23.y);
      }
      acc[dq].x = c01.x; acc[dq].y = c01.y;   // reuse acc as cv storage
      acc[dq].z = c23.x; acc[dq].w = c23.y;
    }
    mn = fminf(mn, swz16(mn));
    mx = fmaxf(mx, swz16(mx));
    mn = fminf(mn, bperm(bpaddr, mn));
    mx = fmaxf(mx, bperm(bpaddr, mx));

    // pass 2: arg = pk_fma(na, cv, base); w = exp2(arg) (0 for masked);
    // sw = sum(w), skw = sum(K*w) with literal K = 16dq+rg; sdw = Cbase*sw - skw.
    const float ralpha = 177.0f * 1.4426950408889634f * fastrcp(mx);
    const float na   = -ralpha;
    const float base = ralpha * mn;
    f32x2 naP;   naP.x = na;   naP.y = na;
    f32x2 baseP; baseP.x = base; baseP.y = base;
    float sw0 = 0.f, sw1 = 0.f, sw2 = 0.f, sw3 = 0.f;
    float sk0 = 0.f, sk1 = 0.f, sk2 = 0.f, sk3 = 0.f;
    #pragma unroll
    for (int dq = 0; dq < 7; ++dq) {
      const f32x2 g01 = pkfma(naP, lo2(acc[dq]), baseP);
      const f32x2 g23 = pkfma(naP, hi2(acc[dq]), baseP);
      const float w0_ = fastexp2(g01.x);
      const float w1_ = fastexp2(g01.y);
      const float w2_ = fastexp2(g23.x);
      const float w3_ = fastexp2(g23.y);
      sw0 += w0_; sw1 += w1_; sw2 += w2_; sw3 += w3_;
      sk0 = fmaf((float)(16 * dq + 0), w0_, sk0);
      sk1 = fmaf((float)(16 * dq + 1), w1_, sk1);
      sk2 = fmaf((float)(16 * dq + 2), w2_, sk2);
      sk3 = fmaf((float)(16 * dq + 3), w3_, sk3);
    }
    float sw  = (sw0 + sw1) + (sw2 + sw3);
    float skw = (sk0 + sk1) + (sk2 + sk3);
    float sdw = fmaf(Cbase, sw, -skw);
    sw  += swz16(sw);
    sdw += swz16(sdw);
    sw  += bperm(bpaddr, sw);
    sdw += bperm(bpaddr, sdw);
    if (gq == 0)
      out[((size_t)bz * IMG_H + h) * IMG_W + w0 + p * 16 + n] = sdw * fastrcp(sw);
  }
}

extern "C" void kernel_launch(void* const* d_in, const int* in_sizes, int n_in,
                              void* d_out, int out_size, void* d_ws, size_t ws_size,
                              hipStream_t stream) {
  (void)in_sizes; (void)n_in; (void)out_size; (void)ws_size;
  const float* xl   = (const float*)d_in[0];
  const float* xr   = (const float*)d_in[1];
  const float* Wt   = (const float*)d_in[2];
  const float* bias = (const float*)d_in[3];
  _Float16* Fc = (_Float16*)d_ws;   // conv features [4,192,640,32] f16 = 31.5 MB
  float* out = (float*)d_out;       // [2,384,1280] f32

  hipLaunchKernelGGL(conv_relu_kernel, dim3(1920), dim3(256), 0, stream,
                     xl, xr, Wt, bias, Fc);
  hipLaunchKernelGGL(disparity_mfma_kernel, dim3(IMG_W / TW, IMG_H, 2), dim3(256), 0, stream,
                     Fc, out);
}

// Round 11
// 76.637 us; speedup vs baseline: 7.1896x; 1.0056x over previous
//
#include <hip/hip_runtime.h>
#include <cstddef>

typedef _Float16 h2    __attribute__((ext_vector_type(2)));
typedef _Float16 half8 __attribute__((ext_vector_type(8)));
typedef float    f32x4 __attribute__((ext_vector_type(4)));
typedef float    f32x2 __attribute__((ext_vector_type(2)));

#define CH    192
#define CWID  640
#define IMG_H 384
#define IMG_W 1280
#define TW    128
#define GR    224      // g rows staged
#define RAWC  179      // 66 fl cols + 113 g cols (+pad to 192)
#define RAWP  192

__device__ __forceinline__ float fastrcp(float x) {
#if __has_builtin(__builtin_amdgcn_rcpf)
  return __builtin_amdgcn_rcpf(x);
#else
  return 1.0f / x;
#endif
}
__device__ __forceinline__ float fastexp2(float x) {
#if __has_builtin(__builtin_amdgcn_exp2f)
  return __builtin_amdgcn_exp2f(x);
#else
  return exp2f(x);
#endif
}
// Cross-lane pair exchange: returns {a,b} such that {a,b} = {own, lane^16 partner}
// (order lane-dependent) — combine with min/max/add. gfx950 permlane = pure VALU,
// no LDS latency; fallbacks use ds_swizzle / ds_bpermute.
__device__ __forceinline__ f32x2 xsw16(float x) {
#if __has_builtin(__builtin_amdgcn_permlane16_swap)
  auto r = __builtin_amdgcn_permlane16_swap(__float_as_uint(x), __float_as_uint(x), false, false);
  f32x2 o; o.x = __uint_as_float(r[0]); o.y = __uint_as_float(r[1]); return o;
#else
  f32x2 o; o.x = x;
  o.y = __uint_as_float((unsigned)__builtin_amdgcn_ds_swizzle((int)__float_as_uint(x), 0x401F));
  return o;
#endif
}
__device__ __forceinline__ f32x2 xsw32(float x) {
#if __has_builtin(__builtin_amdgcn_permlane32_swap)
  auto r = __builtin_amdgcn_permlane32_swap(__float_as_uint(x), __float_as_uint(x), false, false);
  f32x2 o; o.x = __uint_as_float(r[0]); o.y = __uint_as_float(r[1]); return o;
#else
  const int bpa = ((threadIdx.x & 63) ^ 32) << 2;
  f32x2 o; o.x = x;
  o.y = __uint_as_float((unsigned)__builtin_amdgcn_ds_bpermute(bpa, (int)__float_as_uint(x)));
  return o;
#endif
}
// CDNA VOP3P packed-f32 (dual f32 per inst) — hipcc never auto-forms these.
__device__ __forceinline__ f32x2 pkadd(f32x2 a, f32x2 b) {
  f32x2 d; asm("v_pk_add_f32 %0, %1, %2" : "=v"(d) : "v"(a), "v"(b)); return d;
}
__device__ __forceinline__ f32x2 pkfma(f32x2 a, f32x2 b, f32x2 c) {
  f32x2 d; asm("v_pk_fma_f32 %0, %1, %2, %3" : "=v"(d) : "v"(a), "v"(b), "v"(c)); return d;
}
__device__ __forceinline__ float min3f(float a, float b, float c) {
  float d; asm("v_min3_f32 %0, %1, %2, %3" : "=v"(d) : "v"(a), "v"(b), "v"(c)); return d;
}
__device__ __forceinline__ float max3f(float a, float b, float c) {
  float d; asm("v_max3_f32 %0, %1, %2, %3" : "=v"(d) : "v"(a), "v"(b), "v"(c)); return d;
}
__device__ __forceinline__ f32x2 lo2(f32x4 v) { f32x2 r; r.x = v.x; r.y = v.y; return r; }
__device__ __forceinline__ f32x2 hi2(f32x4 v) { f32x2 r; r.x = v.z; r.y = v.w; return r; }

// ---------------- Kernel 1: 3x3 stride-2 SAME conv + bias + ReLU -> f16 ----------------
// VERBATIM R4 conv (measured ~18us, no scratch). R6/R7/R8 restructurings all triggered
// allocator scratch demotion of acc[32] (252MB scratch writes). Do not restructure.
__global__ __launch_bounds__(256)
void conv_relu_kernel(const float* __restrict__ xl, const float* __restrict__ xr,
                      const float* __restrict__ Wt, const float* __restrict__ bias,
                      _Float16* __restrict__ Fc) {
  __shared__ float wl[864];
  __shared__ float bl[32];
  const int tid = threadIdx.x;
  for (int t = tid; t < 864; t += 256) wl[t] = Wt[t];
  if (tid < 32) bl[tid] = bias[tid];
  __syncthreads();

  const int g  = blockIdx.x * 256 + tid;   // [0, 4*192*640)
  const int ow = g % CWID;
  const int t2 = g / CWID;
  const int oh = t2 % CH;
  const int bb = t2 / CH;
  const float* src = (bb < 2) ? (xl + (size_t)bb * IMG_H * IMG_W * 3)
                              : (xr + (size_t)(bb - 2) * IMG_H * IMG_W * 3);
  float acc[32];
  #pragma unroll
  for (int c = 0; c < 32; ++c) acc[c] = bl[c];

  #pragma unroll
  for (int kh = 0; kh < 3; ++kh) {
    const int ir = oh * 2 + kh;
    if (ir >= IMG_H) continue;
    #pragma unroll
    for (int kw = 0; kw < 3; ++kw) {
      const int ic = ow * 2 + kw;
      if (ic >= IMG_W) continue;
      const float* px = src + ((size_t)ir * IMG_W + ic) * 3;
      #pragma unroll
      for (int ci = 0; ci < 3; ++ci) {
        const float v = px[ci];
        const float* wp = &wl[((kh * 3 + kw) * 3 + ci) * 32];
        #pragma unroll
        for (int c8 = 0; c8 < 8; ++c8) {
          const float4 w4 = *(const float4*)(wp + c8 * 4);
          acc[c8 * 4 + 0] = fmaf(v, w4.x, acc[c8 * 4 + 0]);
          acc[c8 * 4 + 1] = fmaf(v, w4.y, acc[c8 * 4 + 1]);
          acc[c8 * 4 + 2] = fmaf(v, w4.z, acc[c8 * 4 + 2]);
          acc[c8 * 4 + 3] = fmaf(v, w4.w, acc[c8 * 4 + 3]);
        }
      }
    }
  }
  _Float16 hv[32];
  #pragma unroll
  for (int c = 0; c < 32; ++c) hv[c] = (_Float16)fmaxf(acc[c], 0.f);
  half8* dst = (half8*)(Fc + (size_t)g * 32);
  #pragma unroll
  for (int q = 0; q < 4; ++q) {
    half8 o;
    #pragma unroll
    for (int e = 0; e < 8; ++e) o[e] = hv[q * 8 + e];
    dst[q] = o;
  }
}

// ------- Kernel 2: f16 MFMA cost volume + soft-argmin -------
// dq0/dq6 band tiles have complementary valid masks (m>=n vs m<n) -> merged into one
// 4-cell select block: no sentinels, no masked exps (24 valid cells/lane exactly).
// Cross-lane reductions via permlane16/32_swap (pure VALU, no LDS wait).
__global__ __launch_bounds__(256, 4)
void disparity_mfma_kernel(const _Float16* __restrict__ Fc, float* __restrict__ out) {
  __shared__ alignas(16) _Float16 raw[RAWP * 16];   // 6 KB: 192 rows x 32B (2 chunks)
  __shared__ alignas(16) _Float16 flH[8 * 512];     // 8 tiles [16][32] f16
  __shared__ alignas(16) _Float16 gH[14 * 512];     // 14 tiles
  __shared__ alignas(16) float As[TW];
  __shared__ alignas(16) float Bs[GR];

  const int tid = threadIdx.x;
  const int w0  = blockIdx.x * TW;
  const int h   = blockIdx.y;
  const int bz  = blockIdx.z;

  // vertical bilinear params (half-pixel, clamped)
  const int hk = h >> 1;
  int r0, r1; float wv0;
  if (h & 1) { r0 = hk; r1 = (hk + 1 > CH - 1) ? CH - 1 : hk + 1; wv0 = 0.75f; }
  else       { r0 = (hk - 1 < 0) ? 0 : hk - 1; r1 = hk;           wv0 = 0.25f; }
  const half8 w0v = (half8)(_Float16)wv0;
  const half8 w1v = (half8)(_Float16)(1.0f - wv0);

  const int vbaseL = (w0 >> 1) + 639;  // fl raw region (t 0..65)
  const int vbaseR = (w0 >> 1) + 592;  // g raw region (t 66..178)

  char* const rawB = (char*)raw;

  // scalar row bases (hoisted 64-bit math)
  const char* const bL0 = (const char*)(Fc + ((size_t)bz * CH + r0) * CWID * 32);
  const char* const bL1 = (const char*)(Fc + ((size_t)bz * CH + r1) * CWID * 32);
  const char* const bR0 = (const char*)(Fc + ((size_t)(bz + 2) * CH + r0) * CWID * 32);
  const char* const bR1 = (const char*)(Fc + ((size_t)(bz + 2) * CH + r1) * CWID * 32);

  // ---- precompute phase-1 row params for row A = tid and row B = tid+256 ----
  const _Float16 h75 = (_Float16)0.75f, h25 = (_Float16)0.25f;
  int a_r0off, a_s0, a_r1off, a_s1, a_swz; half8 a_h0, a_h1; char* a_dst;
  int b_r0off, b_s0, b_r1off, b_s1, b_swz; half8 b_h0, b_h1; char* b_dst;
  {
    const int row = tid;
    const bool isfl = row < TW;
    const int r  = isfl ? row : row - TW;
    const int uv = isfl ? (w0 + r) : (w0 - 95 + r);
    const int uact = uv < 0 ? uv + IMG_W : (uv >= IMG_W ? uv - IMG_W : uv);
    const int up = uv + IMG_W;
    const int vm0 = (up - 1) >> 1;
    int t0 = vm0 - (isfl ? vbaseL : (vbaseR - 66));
    int t1 = t0 + 1;
    if (uact == 0)         t0 = t1;
    if (uact == IMG_W - 1) t1 = t0;
    a_h0 = (half8)((up & 1) ? h75 : h25);
    a_h1 = (half8)((up & 1) ? h25 : h75);
    a_r0off = t0 * 32; a_s0 = (t0 & 1) << 4;
    a_r1off = t1 * 32; a_s1 = (t1 & 1) << 4;
    a_swz = r & 3;
    a_dst = (char*)(isfl ? flH : gH) + (r >> 4) * 1024 + (r & 15) * 64;
  }
  {
    const int row = tid + 256;   // always a g row (256..351) when used
    const int r  = row - TW;
    const int uv = w0 - 95 + r;
    const int uact = uv < 0 ? uv + IMG_W : (uv >= IMG_W ? uv - IMG_W : uv);
    const int up = uv + IMG_W;
    const int vm0 = (up - 1) >> 1;
    int t0 = vm0 - (vbaseR - 66);
    int t1 = t0 + 1;
    if (uact == 0)         t0 = t1;
    if (uact == IMG_W - 1) t1 = t0;
    b_h0 = (half8)((up & 1) ? h75 : h25);
    b_h1 = (half8)((up & 1) ? h25 : h75);
    b_r0off = t0 * 32; b_s0 = (t0 & 1) << 4;
    b_r1off = t1 * 32; b_s1 = (t1 & 1) << 4;
    b_swz = r & 3;
    b_dst = (char*)gH + (r >> 4) * 1024 + (r & 15) * 64;
  }

  float sA = 0.f, sB = 0.f;
  #pragma unroll
  for (int half = 0; half < 2; ++half) {
    // ---- Phase 0: stage 2 channel-chunks of this half + vertical blend ----
    #pragma unroll
    for (int it = 0; it < 2; ++it) {
      const int task = tid + it * 256;     // 384 tasks (192 t x 2 cpos)
      if (it == 0 || tid < 128) {
        const int t    = task >> 1;
        const int cpos = task & 1;
        const int tc   = (t > RAWC - 1) ? RAWC - 1 : t;
        const bool isfl = tc < 66;
        int v = isfl ? (vbaseL + tc) : (vbaseR + tc - 66);   // in [592, 1280]
        v -= (v >= 640) ? 640 : 0;
        v -= (v >= 640) ? 640 : 0;                            // 1280 -> 0 (roll wrap)
        const char* p0 = isfl ? bL0 : bR0;
        const char* p1 = isfl ? bL1 : bR1;
        const int off = (v << 6) + ((half * 2 + cpos) << 4);
        const half8 a0 = *(const half8*)(p0 + off);
        const half8 a1 = *(const half8*)(p1 + off);
        const half8 vv = a0 * w0v + a1 * w1v;
        *(half8*)(rawB + t * 32 + ((cpos ^ (t & 1)) << 4)) = vv;
      }
    }
    __syncthreads();

    // ---- Phase 1: horizontal blend + tiles + norm partials (this half) ----
    #pragma unroll
    for (int cpos = 0; cpos < 2; ++cpos) {
      const int c16 = half * 2 + cpos;
      const int cb  = cpos << 4;
      {
        const half8 a = *(const half8*)(rawB + a_r0off + (cb ^ a_s0));
        const half8 b = *(const half8*)(rawB + a_r1off + (cb ^ a_s1));
        const half8 v = a * a_h0 + b * a_h1;
        #pragma unroll
        for (int e = 0; e < 4; ++e) {
          h2 pe = {v[2 * e], v[2 * e + 1]};
#if __has_builtin(__builtin_amdgcn_fdot2)
          sA = __builtin_amdgcn_fdot2(pe, pe, sA, false);
#else
          sA += (float)pe[0] * (float)pe[0] + (float)pe[1] * (float)pe[1];
#endif
        }
        *(half8*)(a_dst + ((c16 ^ a_swz) << 4)) = v;
      }
      if (tid < TW + GR - 256) {
        const half8 a = *(const half8*)(rawB + b_r0off + (cb ^ b_s0));
        const half8 b = *(const half8*)(rawB + b_r1off + (cb ^ b_s1));
        const half8 v = a * b_h0 + b * b_h1;
        #pragma unroll
        for (int e = 0; e < 4; ++e) {
          h2 pe = {v[2 * e], v[2 * e + 1]};
#if __has_builtin(__builtin_amdgcn_fdot2)
          sB = __builtin_amdgcn_fdot2(pe, pe, sB, false);
#else
          sB += (float)pe[0] * (float)pe[0] + (float)pe[1] * (float)pe[1];
#endif
        }
        *(half8*)(b_dst + ((c16 ^ b_swz) << 4)) = v;
      }
    }
    __syncthreads();   // raw reads done before next half overwrites
  }
  if (tid < TW) As[tid] = sA; else Bs[tid - TW] = sA;
  if (tid < TW + GR - 256) Bs[tid + 256 - TW] = sB;
  __syncthreads();

  // ---- Phase 2: MFMA band + per-pixel soft-argmin ----
  const int lane = tid & 63;
  const int wid  = tid >> 6;
  const int n  = lane & 15;   // fl row within tile (C col)
  const int gq = lane >> 4;   // k-slice / C row group
  const int foffB = n * 64 + ((gq ^ (n & 3)) << 4);
  const float Cbase = (float)(95 - 4 * gq + n);   // kf = Cbase - (16*dq + rg)

  // merged dq0/dq6 selection constants (fixed per thread, shared by both pp):
  // m = 4*gq + rg; sel = (m >= n) -> use dq0 (k = m-n), else dq6 (k = 96+m-n).
  const int mmb = gq * 4;
  const bool s0 = (mmb + 0) >= n, s1 = (mmb + 1) >= n;
  const bool s2 = (mmb + 2) >= n, s3 = (mmb + 3) >= n;
  const float kf0 = s0 ? 0.f : 96.f;
  const float kf1 = s1 ? 1.f : 97.f;
  const float kf2 = s2 ? 2.f : 98.f;
  const float kf3 = s3 ? 3.f : 99.f;

  #pragma unroll
  for (int pp = 0; pp < 2; ++pp) {
    const int p = wid * 2 + pp;          // i-tile 0..7
    const half8 bfrag = *(const half8*)((const char*)flH + p * 1024 + foffB);
    f32x4 acc[7];
    #pragma unroll
    for (int dq = 0; dq < 7; ++dq) {
      const half8 afrag = *(const half8*)((const char*)gH + (p + dq) * 1024 + foffB);
      f32x4 z = {0.f, 0.f, 0.f, 0.f};
      acc[dq] = __builtin_amdgcn_mfma_f32_16x16x32_f16(afrag, bfrag, z, 0, 0, 0);
    }

    // pass 1: merged dq0/dq6 cells (all valid, no sentinels) + packed dq1..5
    const float Ai = As[p * 16 + n];
    const f32x4 b40 = *(const f32x4*)(&Bs[p * 16 + mmb]);
    const f32x4 b46 = *(const f32x4*)(&Bs[(p + 6) * 16 + mmb]);
    const float cm0 = fmaf(-2.f, s0 ? acc[0].x : acc[6].x, Ai + (s0 ? b40.x : b46.x));
    const float cm1 = fmaf(-2.f, s1 ? acc[0].y : acc[6].y, Ai + (s1 ? b40.y : b46.y));
    const float cm2 = fmaf(-2.f, s2 ? acc[0].z : acc[6].z, Ai + (s2 ? b40.z : b46.z));
    const float cm3 = fmaf(-2.f, s3 ? acc[0].w : acc[6].w, Ai + (s3 ? b40.w : b46.w));
    float mn = min3f(fminf(cm0, cm1), cm2, cm3);
    float mx = max3f(fmaxf(cm0, cm1), cm2, cm3);

    f32x2 AiP; AiP.x = Ai; AiP.y = Ai;
    f32x2 m2P; m2P.x = -2.f; m2P.y = -2.f;
    #pragma unroll
    for (int dq = 1; dq < 6; ++dq) {
      const f32x4 b4 = *(const f32x4*)(&Bs[(p + dq) * 16 + mmb]);
      const f32x2 c01 = pkfma(m2P, lo2(acc[dq]), pkadd(AiP, lo2(b4)));
      const f32x2 c23 = pkfma(m2P, hi2(acc[dq]), pkadd(AiP, hi2(b4)));
      mn = min3f(mn, c01.x, c01.y);
      mn = min3f(mn, c23.x, c23.y);
      mx = max3f(mx, c01.x, c01.y);
      mx = max3f(mx, c23.x, c23.y);
      acc[dq].x = c01.x; acc[dq].y = c01.y;   // reuse acc as cv storage
      acc[dq].z = c23.x; acc[dq].w = c23.y;
    }
    // cross-lane min/max over the 4 gq lanes: permlane (VALU), no LDS wait
    f32x2 t;
    t = xsw16(mn); mn = fminf(t.x, t.y);
    t = xsw32(mn); mn = fminf(t.x, t.y);
    t = xsw16(mx); mx = fmaxf(t.x, t.y);
    t = xsw32(mx); mx = fmaxf(t.x, t.y);

    // pass 2: w = exp2(na*cv + base); sw = sum(w); skw = sum(kf*w);
    // sdw = Cbase*sw - skw  (kf literal for dq1..5, selected VGPR for merged)
    const float ralpha = 177.0f * 1.4426950408889634f * fastrcp(mx);
    const float na   = -ralpha;
    const float base = ralpha * mn;
    f32x2 naP;   naP.x = na;   naP.y = na;
    f32x2 baseP; baseP.x = base; baseP.y = base;
    const float w0_ = fastexp2(fmaf(na, cm0, base));
    const float w1_ = fastexp2(fmaf(na, cm1, base));
    const float w2_ = fastexp2(fmaf(na, cm2, base));
    const float w3_ = fastexp2(fmaf(na, cm3, base));
    float sw0 = w0_, sw1 = w1_, sw2 = w2_, sw3 = w3_;
    float sk0 = kf0 * w0_;
    float sk1 = kf1 * w1_;
    float sk2 = kf2 * w2_;
    float sk3 = kf3 * w3_;
    #pragma unroll
    for (int dq = 1; dq < 6; ++dq) {
      const f32x2 g01 = pkfma(naP, lo2(acc[dq]), baseP);
      const f32x2 g23 = pkfma(naP, hi2(acc[dq]), baseP);
      const float u0 = fastexp2(g01.x);
      const float u1 = fastexp2(g01.y);
      const float u2 = fastexp2(g23.x);
      const float u3 = fastexp2(g23.y);
      sw0 += u0; sw1 += u1; sw2 += u2; sw3 += u3;
      sk0 = fmaf((float)(16 * dq + 0), u0, sk0);
      sk1 = fmaf((float)(16 * dq + 1), u1, sk1);
      sk2 = fmaf((float)(16 * dq + 2), u2, sk2);
      sk3 = fmaf((float)(16 * dq + 3), u3, sk3);
    }
    float sw  = (sw0 + sw1) + (sw2 + sw3);
    float skw = (sk0 + sk1) + (sk2 + sk3);
    float sdw = fmaf(Cbase, sw, -skw);
    t = xsw16(sw);  sw  = t.x + t.y;
    t = xsw16(sdw); sdw = t.x + t.y;
    t = xsw32(sw);  sw  = t.x + t.y;
    t = xsw32(sdw); sdw = t.x + t.y;
    if (gq == 0)
      out[((size_t)bz * IMG_H + h) * IMG_W + w0 + p * 16 + n] = sdw * fastrcp(sw);
  }
}

extern "C" void kernel_launch(void* const* d_in, const int* in_sizes, int n_in,
                              void* d_out, int out_size, void* d_ws, size_t ws_size,
                              hipStream_t stream) {
  (void)in_sizes; (void)n_in; (void)out_size; (void)ws_size;
  const float* xl   = (const float*)d_in[0];
  const float* xr   = (const float*)d_in[1];
  const float* Wt   = (const float*)d_in[2];
  const float* bias = (const float*)d_in[3];
  _Float16* Fc = (_Float16*)d_ws;   // conv features [4,192,640,32] f16 = 31.5 MB
  float* out = (float*)d_out;       // [2,384,1280] f32

  hipLaunchKernelGGL(conv_relu_kernel, dim3(1920), dim3(256), 0, stream,
                     xl, xr, Wt, bias, Fc);
  hipLaunchKernelGGL(disparity_mfma_kernel, dim3(IMG_W / TW, IMG_H, 2), dim3(256), 0, stream,
                     Fc, out);
}